// Round 11
// baseline (288.395 us; speedup 1.0000x reference)
//
#include <hip/hip_runtime.h>
#include <hip/hip_bf16.h>

typedef unsigned short u16;

#define BDIM 8
#define LDIM 8192
#define KDIM 256      // C
#define DDIM 256      // D
#define MTOT 65536    // B*L
#define NDIM 1536     // 6*D
#define TCH  32       // scan chunk length
#define NCH  256      // chunks per sequence
#define NSUP 16       // supers per sequence (NCH/16)

// Physical column layout of G (per m-row), dir f in {0,1}, base = f*768:
//   [base + 2d + 0] = h-gate col d   [base + 2d + 1] = z-gate col d  (d<256)
//   [base + 512 + d] = s-gate col d
// WcatT rows are phi-permuted (j*16+r -> r*4+j within each 64-col block) so
// the gemm epilogue writes 4 contiguous u16 per lane. G layout UNCHANGED.

typedef float floatx4 __attribute__((ext_vector_type(4)));
typedef short bf16x8 __attribute__((ext_vector_type(8)));
typedef unsigned int u32x4 __attribute__((ext_vector_type(4)));
typedef unsigned int u32x2 __attribute__((ext_vector_type(2)));

__device__ __forceinline__ u16 f2bf(float f) {
  union { __hip_bfloat16 h; u16 u; } c;
  c.h = __float2bfloat16(f);
  return c.u;
}
__device__ __forceinline__ float bf2f(u16 u) {
  union { unsigned int i; float f; } c;
  c.i = ((unsigned int)u) << 16;
  return c.f;
}
__device__ __forceinline__ float sigmoidf_fast(float x) {
  return __builtin_amdgcn_rcpf(1.0f + __expf(-x));
}
__device__ __forceinline__ void gll16(const void* g, void* l) {
  __builtin_amdgcn_global_load_lds((const __attribute__((address_space(1))) void*)g,
                                   (__attribute__((address_space(3))) void*)l, 16, 0, 0);
}

// ---------------------------------------------------------------------------
// Prep: weights only (xs conversion now fused into the gemm's A staging).
// WcatT row n holds the weight column for PHYSICAL G col phi(n).
// ---------------------------------------------------------------------------
__global__ void prep_weights(const float* __restrict__ Wh1, const float* __restrict__ Wz1,
                             const float* __restrict__ Ws1, const float* __restrict__ Wh_1,
                             const float* __restrict__ Wz_1, const float* __restrict__ Ws_1,
                             const float* __restrict__ bh1, const float* __restrict__ bz1,
                             const float* __restrict__ bs1, const float* __restrict__ bh_1,
                             const float* __restrict__ bz_1, const float* __restrict__ bs_1,
                             u16* __restrict__ WcatT, float* __restrict__ bcat) {
  const int n = blockIdx.x;       // WcatT row (GEMM B-row) 0..1535
  const int k = threadIdx.x;      // 0..255
  const int nn = n & 63;
  const int p = (n & ~63) | ((nn & 15) << 2) | (nn >> 4);   // physical col
  const int dir = p / 768, r = p % 768;
  int d; const float* W; const float* bb;
  if (r < 512) {
    d = r >> 1;
    if (r & 1) { W = dir ? Wz_1 : Wz1; bb = dir ? bz_1 : bz1; }
    else       { W = dir ? Wh_1 : Wh1; bb = dir ? bh_1 : bh1; }
  } else {
    d = r - 512;
    W = dir ? Ws_1 : Ws1; bb = dir ? bs_1 : bs1;
  }
  WcatT[(size_t)n * KDIM + k] = f2bf(W[k * DDIM + d]);
  if (k == 0) bcat[p] = bb[d];
}

// ---------------------------------------------------------------------------
// GEMM: 128x128 tile, BK=64, XCD-swizzled grid. A is staged DIRECTLY from
// xs fp32 via global_load_lds (ASYNC -- same barrier pipeline as the proven
// bf16 path; r5/r6's failure was SYNCHRONOUS register loads) into a 32KB
// fp32 A-tile with a 4-bit XOR swizzle (q ^ row&15, 2-way bank aliasing =
// free). Fragments convert fp32->bf16 at ds_read time (same RNE convert as
// convert_xs -> bit-identical numerics); the extra VALU overlaps the MFMA
// pipe. This deletes the 96MB xs->Abf conversion pass entirely.
// Epilogue: unchanged r4 form (LDS C-tile, free-drain barrier, 16B stores,
// fused phaseA chunk-summary; s-gate blocks store direct from regs).
// ---------------------------------------------------------------------------
__global__ __launch_bounds__(256) void gemm_kernel(const float* __restrict__ xs,
                                                   const u16* __restrict__ WcatT,
                                                   const float* __restrict__ bcat,
                                                   u16* __restrict__ G,
                                                   float* __restrict__ Acc,
                                                   float* __restrict__ Bcc) {
  __shared__ __align__(16) u16 sm[24576];   // 48 KB: As fp32 32KB + Bs bf16 16KB
  float* Asf = (float*)sm;                  // [128][64] fp32, quad-swizzled
  u16* Bs = sm + 16384;                     // byte 32768..49152
  const int tid = threadIdx.x;
  const int lane = tid & 63, wave = tid >> 6;
  const int wm = wave >> 1, wn = wave & 1;
  const int q = lane >> 4, r = lane & 15;

  const int xcd = blockIdx.x & 7;
  const int li  = blockIdx.x >> 3;
  const int mt  = xcd * 64 + li / 12;
  const int nt  = li % 12;
  const int m0 = mt * 128, n0 = nt * 128;

  // A staging: 2048 16B-slots (128 rows x 16 quads), 8 per thread.
  // Slot bi holds logical k-quad (bi&15)^(row&15) of row bi>>4.
  const float* gA[8]; float* lA[8];
#pragma unroll
  for (int j = 0; j < 8; j++) {
    const int bi = wave * 512 + j * 64 + lane;
    const int row = bi >> 4;
    const int kq = (bi & 15) ^ (row & 15);       // logical k-quad
    gA[j] = xs + (size_t)(m0 + row) * KDIM + kq * 4;
    lA[j] = Asf + bi * 4;
  }
  // B staging: unchanged bf16 path (1024 slots, 4 per thread, 3-bit swizzle).
  const u16* gB[4]; u16* lB[4];
#pragma unroll
  for (int j = 0; j < 4; j++) {
    const int bi = wave * 256 + j * 64 + lane;
    const int row = bi >> 3;
    const int kq = (bi & 7) ^ (row & 7);
    gB[j] = WcatT + (size_t)(n0 + row) * KDIM + kq * 8;
    lB[j] = Bs + bi * 8;
  }

  floatx4 acc[4][4];
  floatx4 z4 = {0.f, 0.f, 0.f, 0.f};
#pragma unroll
  for (int i = 0; i < 4; i++)
#pragma unroll
    for (int j = 0; j < 4; j++) acc[i][j] = z4;

  for (int k0 = 0; k0 < KDIM; k0 += 64) {
#pragma unroll
    for (int j = 0; j < 4; j++) gll16(gB[j] + k0, lB[j]);
#pragma unroll
    for (int j = 0; j < 8; j++) gll16(gA[j] + k0, lA[j]);
    __syncthreads();
#pragma unroll
    for (int kk = 0; kk < 2; kk++) {
      bf16x8 af[4], bv[4];
#pragma unroll
      for (int i = 0; i < 4; i++) {
        const int row = wm * 64 + i * 16 + r;
        const int jq = kk * 8 + q * 2;            // even
        const int p0 = jq ^ (row & 15);
        const int p1 = (jq + 1) ^ (row & 15);
        const floatx4 fa0 = *(const floatx4*)(Asf + (row * 16 + p0) * 4);
        const floatx4 fa1 = *(const floatx4*)(Asf + (row * 16 + p1) * 4);
        union { u16 u[8]; bf16x8 v; } ua;
        ua.u[0] = f2bf(fa0[0]); ua.u[1] = f2bf(fa0[1]);
        ua.u[2] = f2bf(fa0[2]); ua.u[3] = f2bf(fa0[3]);
        ua.u[4] = f2bf(fa1[0]); ua.u[5] = f2bf(fa1[1]);
        ua.u[6] = f2bf(fa1[2]); ua.u[7] = f2bf(fa1[3]);
        af[i] = ua.v;
      }
#pragma unroll
      for (int j = 0; j < 4; j++) {
        const int row = wn * 64 + j * 16 + r;
        bv[j] = *(const bf16x8*)(Bs + (row * 8 + ((kk * 4 + q) ^ (row & 7))) * 8);
      }
#pragma unroll
      for (int i = 0; i < 4; i++)
#pragma unroll
        for (int j = 0; j < 4; j++)
          acc[i][j] = __builtin_amdgcn_mfma_f32_16x16x32_bf16(af[i], bv[j], acc[i][j], 0, 0, 0);
    }
    __syncthreads();
  }

  // Epilogue. C/D layout: col = lane&15, row = (lane>>4)*4 + reg  [m89/m91].
  const int pcol = wn * 64 + (r << 2);
  const float4 bv4 = *(const float4*)(bcat + n0 + pcol);
  const int hz = (n0 % 768) < 512;   // block-uniform

  if (hz) {
    // Stage bias-added bf16 C-tile to LDS (reuses As region; all waves are
    // past the last k-loop barrier so As is dead).
#pragma unroll
    for (int i = 0; i < 4; i++) {
#pragma unroll
      for (int reg = 0; reg < 4; reg++) {
        const int lrow = wm * 64 + i * 16 + q * 4 + reg;
        union { u16 u[4]; u32x2 v; } t;
        t.u[0] = f2bf(acc[i][0][reg] + bv4.x);
        t.u[1] = f2bf(acc[i][1][reg] + bv4.y);
        t.u[2] = f2bf(acc[i][2][reg] + bv4.z);
        t.u[3] = f2bf(acc[i][3][reg] + bv4.w);
        *(u32x2*)(sm + lrow * 128 + pcol) = t.v;
      }
    }

    __syncthreads();   // vmcnt already 0 -> free drain; orders the LDS tile

    // Coalesced G write: 8 passes x 16B/thread, 256B segments per row.
#pragma unroll
    for (int p = 0; p < 8; p++) {
      const int idx = p * 2048 + tid * 8;        // u16 index within tile
      const int row = idx >> 7, col = idx & 127;
      const u32x4 v = *(const u32x4*)(sm + idx);
      *(u32x4*)(G + (size_t)(m0 + row) * NDIM + n0 + col) = v;
    }

    // 4 chunks (one per wave) x 64 d (one per lane); 32-step affine summary.
    const int cc = wave;                 // chunk within tile 0..3
    const int dd = lane;                 // d within tile 0..63
    const int dirn = n0 / 768;
    const int dbase = (n0 % 768) >> 1;   // 0,64,128,192
    const int bb = m0 >> 13;             // batch
    const int c0 = (m0 & 8191) >> 5;     // first chunk of tile
    float h = 0.f, P = 1.f;
#pragma unroll 8
    for (int i = 0; i < TCH; ++i) {
      const int tl = dirn ? (TCH - 1 - i) : i;
      const unsigned int hzv = *(const unsigned int*)(sm + (cc * 32 + tl) * 128 + dd * 2);
      const float z = sigmoidf_fast(bf2f((u16)(hzv >> 16)));
      const float a = 1.f - z;
      h = fmaf(a, h, z * bf2f((u16)(hzv & 0xffffu)));
      P *= a;
    }
    const size_t u = (size_t)dirn * 2048 + (size_t)bb * 256 + (size_t)(c0 + cc);
    Acc[u * 256 + dbase + dd] = P;
    Bcc[u * 256 + dbase + dd] = h;
  } else {
    // s-gate block: direct 8B stores from registers, no extra barrier.
#pragma unroll
    for (int i = 0; i < 4; i++) {
#pragma unroll
      for (int reg = 0; reg < 4; reg++) {
        const int lrow = wm * 64 + i * 16 + q * 4 + reg;
        union { u16 u[4]; u32x2 v; } t;
        t.u[0] = f2bf(acc[i][0][reg] + bv4.x);
        t.u[1] = f2bf(acc[i][1][reg] + bv4.y);
        t.u[2] = f2bf(acc[i][2][reg] + bv4.z);
        t.u[3] = f2bf(acc[i][3][reg] + bv4.w);
        *(u32x2*)(G + (size_t)(m0 + lrow) * NDIM + n0 + pcol) = t.v;
      }
    }
  }
}

// ---------------------------------------------------------------------------
// Scan phase B1: two-level scan, level 1. Per (dir,b,super), overwrite
// Acc/Bcc in place with within-super prefix affines; emit super summary.
// ---------------------------------------------------------------------------
__global__ __launch_bounds__(256) void scan_phaseB1(float* __restrict__ Acc,
                                                    float* __restrict__ Bcc,
                                                    float* __restrict__ Asum,
                                                    float* __restrict__ Bsum) {
  const int d = threadIdx.x;
  const int s   = blockIdx.x & 15;
  const int b   = (blockIdx.x >> 4) & 7;
  const int dir = blockIdx.x >> 7;
  const size_t ubase = ((size_t)dir * BDIM + b) * NCH;
  float a[16], bb[16];
#pragma unroll
  for (int i = 0; i < 16; ++i) {
    const int c = dir ? (NCH - 1 - (s * 16 + i)) : (s * 16 + i);
    const size_t idx = (ubase + c) * DDIM + d;
    a[i] = Acc[idx]; bb[i] = Bcc[idx];
  }
  float A = 1.f, Bv = 0.f;
#pragma unroll
  for (int i = 0; i < 16; ++i) {
    const int c = dir ? (NCH - 1 - (s * 16 + i)) : (s * 16 + i);
    const size_t idx = (ubase + c) * DDIM + d;
    Acc[idx] = A; Bcc[idx] = Bv;
    Bv = fmaf(a[i], Bv, bb[i]);
    A  = a[i] * A;
  }
  const size_t sidx = (((size_t)dir * BDIM + b) * NSUP + s) * DDIM + d;
  Asum[sidx] = A; Bsum[sidx] = Bv;
}

// ---------------------------------------------------------------------------
// Scan phase C (B2 folded in): block = one (b,c) chunk, 256 thr, 2 d/lane,
// both dirs concurrent. Entry: chain <=15 L2-resident super summaries from
// h0, then the chunk prefix affine. G loads batched 16-deep. Staggered
// 2-phase LDS exchange. Unchanged from round 10.
// ---------------------------------------------------------------------------
__global__ __launch_bounds__(256) void scan_phaseC(const u16* __restrict__ G,
                                                   const float* __restrict__ Acc,
                                                   const float* __restrict__ Bcc,
                                                   const float* __restrict__ Asum,
                                                   const float* __restrict__ Bsum,
                                                   const float* __restrict__ h01,
                                                   const float* __restrict__ h0_1,
                                                   float* __restrict__ out) {
  __shared__ float obuf[TCH * 256];   // 32 KB
  const int c = blockIdx.x & 255, b = blockIdx.x >> 8;
  const int dir = threadIdx.x >> 7;                       // waves 0-1 fwd, 2-3 bwd
  const int ld  = threadIdx.x & 127;                      // 0..127 within dir
  const int d0 = ld * 2;

  // --- entry state: h0 -> chain supers < sp -> chunk prefix affine ---
  const int sp = dir ? ((NCH - 1 - c) >> 4) : (c >> 4);
  const float2 hh = dir ? *(const float2*)(h0_1 + d0) : *(const float2*)(h01 + d0);
  float ha = hh.x, hb = hh.y;
  const size_t sbase = ((size_t)dir * BDIM + b) * NSUP;
  for (int s = 0; s < sp; ++s) {
    const float2 As2 = *(const float2*)(Asum + (sbase + s) * DDIM + d0);
    const float2 Bs2 = *(const float2*)(Bsum + (sbase + s) * DDIM + d0);
    ha = fmaf(As2.x, ha, Bs2.x);
    hb = fmaf(As2.y, hb, Bs2.y);
  }
  const int u = dir * 2048 + b * 256 + c;
  const float2 ap = *(const float2*)(Acc + (size_t)u * 256 + d0);
  const float2 bp = *(const float2*)(Bcc + (size_t)u * 256 + d0);
  float h0 = fmaf(ap.x, ha, bp.x);
  float h1 = fmaf(ap.y, hb, bp.y);

  const u16* ghz = G + (size_t)b * LDIM * NDIM + dir * 768 + d0 * 2;
  const u16* gs  = G + (size_t)b * LDIM * NDIM + dir * 768 + 512 + d0;

  // Phase 1: fwd tl=0..15, bwd tl=31..16 (disjoint obuf rows).
  {
    uint2 hzr[16]; unsigned int sr[16];
#pragma unroll
    for (int i = 0; i < 16; ++i) {
      const int tl = dir ? (TCH - 1 - i) : i;
      const int t = c * TCH + tl;
      hzr[i] = *(const uint2*)(ghz + (size_t)t * NDIM);
      sr[i]  = *(const unsigned int*)(gs + (size_t)t * NDIM);
    }
#pragma unroll
    for (int i = 0; i < 16; ++i) {
      const int tl = dir ? (TCH - 1 - i) : i;
      const float z0 = sigmoidf_fast(bf2f((u16)(hzr[i].x >> 16)));
      const float z1 = sigmoidf_fast(bf2f((u16)(hzr[i].y >> 16)));
      h0 = fmaf(1.f - z0, h0, z0 * bf2f((u16)(hzr[i].x & 0xffffu)));
      h1 = fmaf(1.f - z1, h1, z1 * bf2f((u16)(hzr[i].y & 0xffffu)));
      float2 o;
      o.x = h0 * sigmoidf_fast(bf2f((u16)(sr[i] & 0xffffu)));
      o.y = h1 * sigmoidf_fast(bf2f((u16)(sr[i] >> 16)));
      *(float2*)(obuf + tl * 256 + d0) = o;
    }
  }

  __syncthreads();

  // Phase 2: fwd tl=16..31, bwd tl=15..0; merge with other dir, store out.
  {
    uint2 hzr[16]; unsigned int sr[16];
#pragma unroll
    for (int i = 0; i < 16; ++i) {
      const int tl = dir ? (TCH - 1 - (16 + i)) : (16 + i);
      const int t = c * TCH + tl;
      hzr[i] = *(const uint2*)(ghz + (size_t)t * NDIM);
      sr[i]  = *(const unsigned int*)(gs + (size_t)t * NDIM);
    }
#pragma unroll
    for (int i = 0; i < 16; ++i) {
      const int tl = dir ? (TCH - 1 - (16 + i)) : (16 + i);
      const int t = c * TCH + tl;
      const float z0 = sigmoidf_fast(bf2f((u16)(hzr[i].x >> 16)));
      const float z1 = sigmoidf_fast(bf2f((u16)(hzr[i].y >> 16)));
      h0 = fmaf(1.f - z0, h0, z0 * bf2f((u16)(hzr[i].x & 0xffffu)));
      h1 = fmaf(1.f - z1, h1, z1 * bf2f((u16)(hzr[i].y & 0xffffu)));
      const float o0 = h0 * sigmoidf_fast(bf2f((u16)(sr[i] & 0xffffu)));
      const float o1 = h1 * sigmoidf_fast(bf2f((u16)(sr[i] >> 16)));
      const float2 other = *(const float2*)(obuf + tl * 256 + d0);
      float2 res;
      res.x = o0 + other.x;
      res.y = o1 + other.y;
      *(float2*)(out + ((size_t)b * LDIM + t) * DDIM + d0) = res;
    }
  }
}

extern "C" void kernel_launch(void* const* d_in, const int* in_sizes, int n_in,
                              void* d_out, int out_size, void* d_ws, size_t ws_size,
                              hipStream_t stream) {
  const float* xs   = (const float*)d_in[0];
  const float* Wh1  = (const float*)d_in[1];
  const float* bh1  = (const float*)d_in[2];
  const float* Wz1  = (const float*)d_in[3];
  const float* bz1  = (const float*)d_in[4];
  const float* Ws1  = (const float*)d_in[5];
  const float* bs1  = (const float*)d_in[6];
  const float* h01  = (const float*)d_in[7];
  const float* Wh_1 = (const float*)d_in[8];
  const float* bh_1 = (const float*)d_in[9];
  const float* Wz_1 = (const float*)d_in[10];
  const float* bz_1 = (const float*)d_in[11];
  const float* Ws_1 = (const float*)d_in[12];
  const float* bs_1 = (const float*)d_in[13];
  const float* h0_1 = (const float*)d_in[14];
  float* out = (float*)d_out;

  char* ws = (char*)d_ws;
  u16* WcatT = (u16*)ws;   ws += (size_t)NDIM * KDIM * 2;   // 0.75 MB
  float* bcat = (float*)ws; ws += (size_t)NDIM * 4;         // 6 KB
  u16* G = (u16*)ws;       ws += (size_t)MTOT * NDIM * 2;   // 192 MB

  const size_t sumElems = (size_t)2 * BDIM * NCH * DDIM;    // 1M floats = 4 MB
  const size_t supElems = (size_t)2 * BDIM * NSUP * DDIM;   // 64K floats = 256 KB
  float* Acc  = (float*)ws; ws += sumElems * 4;
  float* Bcc  = (float*)ws; ws += sumElems * 4;
  float* Asum = (float*)ws; ws += supElems * 4;
  float* Bsum = (float*)ws; ws += supElems * 4;
  if ((size_t)(ws - (char*)d_ws) > ws_size) return;

  prep_weights<<<dim3(NDIM), dim3(KDIM), 0, stream>>>(
      Wh1, Wz1, Ws1, Wh_1, Wz_1, Ws_1, bh1, bz1, bs1, bh_1, bz_1, bs_1, WcatT, bcat);
  gemm_kernel<<<dim3(6144), dim3(256), 0, stream>>>(xs, WcatT, bcat, G, Acc, Bcc);
  scan_phaseB1<<<dim3(256), dim3(DDIM), 0, stream>>>(Acc, Bcc, Asum, Bsum);
  scan_phaseC<<<dim3(2048), dim3(256), 0, stream>>>(G, Acc, Bcc, Asum, Bsum, h01, h0_1, out);
}

// Round 13
// 267.028 us; speedup vs baseline: 1.0800x; 1.0800x over previous
//
#include <hip/hip_runtime.h>
#include <hip/hip_bf16.h>

typedef unsigned short u16;

#define BDIM 8
#define LDIM 8192
#define KDIM 256      // C
#define DDIM 256      // D
#define MTOT 65536    // B*L
#define NDIM 1536     // 6*D
#define TCH  32       // scan chunk length
#define NCH  256      // chunks per sequence
#define NSUP 16       // supers per sequence (NCH/16)

// Physical column layout of G (per m-row), dir f in {0,1}, base = f*768:
//   [base + 2d + 0] = h-gate col d   [base + 2d + 1] = z-gate col d  (d<256)
//   [base + 512 + d] = s-gate col d
// WcatT rows are phi-permuted (j*16+r -> r*4+j within each 64-col block) so
// the gemm epilogue writes 4 contiguous u16 per lane. G layout UNCHANGED.

typedef float floatx4 __attribute__((ext_vector_type(4)));
typedef short bf16x8 __attribute__((ext_vector_type(8)));
typedef unsigned int u32x4 __attribute__((ext_vector_type(4)));
typedef unsigned int u32x2 __attribute__((ext_vector_type(2)));

__device__ __forceinline__ u16 f2bf(float f) {
  union { __hip_bfloat16 h; u16 u; } c;
  c.h = __float2bfloat16(f);
  return c.u;
}
__device__ __forceinline__ float bf2f(u16 u) {
  union { unsigned int i; float f; } c;
  c.i = ((unsigned int)u) << 16;
  return c.f;
}
__device__ __forceinline__ float sigmoidf_fast(float x) {
  return __builtin_amdgcn_rcpf(1.0f + __expf(-x));
}
__device__ __forceinline__ void gll16(const u16* g, u16* l) {
  __builtin_amdgcn_global_load_lds((const __attribute__((address_space(1))) void*)g,
                                   (__attribute__((address_space(3))) void*)l, 16, 0, 0);
}

// ---------------------------------------------------------------------------
// Fused prep: blocks [0,NDIM) build WcatT/bcat (phi-permuted weight rows);
// blocks [NDIM, NDIM+2048) convert xs fp32 -> bf16 Abf, grid-stride x4.
// NOTE: keeping the conversion as a SEPARATE streaming pass is deliberate --
// three in-gemm fusion variants (r5 sync regs, r6 reg prefetch, r11 async
// fp32 LDS) all regressed the gemm by 40-50us vs the ~20us this pass costs.
// ---------------------------------------------------------------------------
__global__ void prep_conv(const float* __restrict__ Wh1, const float* __restrict__ Wz1,
                          const float* __restrict__ Ws1, const float* __restrict__ Wh_1,
                          const float* __restrict__ Wz_1, const float* __restrict__ Ws_1,
                          const float* __restrict__ bh1, const float* __restrict__ bz1,
                          const float* __restrict__ bs1, const float* __restrict__ bh_1,
                          const float* __restrict__ bz_1, const float* __restrict__ bs_1,
                          u16* __restrict__ WcatT, float* __restrict__ bcat,
                          const float* __restrict__ xs, u16* __restrict__ Abf) {
  if (blockIdx.x < NDIM) {
    const int n = blockIdx.x;       // WcatT row (GEMM B-row) 0..1535
    const int k = threadIdx.x;      // 0..255
    const int nn = n & 63;
    const int p = (n & ~63) | ((nn & 15) << 2) | (nn >> 4);   // physical col
    const int dir = p / 768, r = p % 768;
    int d; const float* W; const float* bb;
    if (r < 512) {
      d = r >> 1;
      if (r & 1) { W = dir ? Wz_1 : Wz1; bb = dir ? bz_1 : bz1; }
      else       { W = dir ? Wh_1 : Wh1; bb = dir ? bh_1 : bh1; }
    } else {
      d = r - 512;
      W = dir ? Ws_1 : Ws1; bb = dir ? bs_1 : bs1;
    }
    WcatT[(size_t)n * KDIM + k] = f2bf(W[k * DDIM + d]);
    if (k == 0) bcat[p] = bb[d];
  } else {
    const int cb = blockIdx.x - NDIM;               // 0..2047
#pragma unroll
    for (int pass = 0; pass < 4; ++pass) {
      size_t i = ((size_t)(pass * 2048 + cb) * 256 + threadIdx.x) * 8;
      const float4* s = (const float4*)(xs + i);
      float4 f0 = s[0], f1 = s[1];
      union { u16 u[8]; u32x4 v; } t;
      t.u[0] = f2bf(f0.x); t.u[1] = f2bf(f0.y); t.u[2] = f2bf(f0.z); t.u[3] = f2bf(f0.w);
      t.u[4] = f2bf(f1.x); t.u[5] = f2bf(f1.y); t.u[6] = f2bf(f1.z); t.u[7] = f2bf(f1.w);
      *(u32x4*)(Abf + i) = t.v;
    }
  }
}

// ---------------------------------------------------------------------------
// GEMM: 128x128 tile, BK=64, global_load_lds staging, XCD-swizzled grid,
// plain stores (NT regressed r8). Epilogue: hz-blocks stage C-tile to LDS,
// free-drain __syncthreads (vmcnt already 0), 16B coalesced G stores from
// LDS readback, fused phaseA chunk-summary scan. s-gate blocks store direct
// from regs. This is the proven r4/r10 form: 76-78us, ~3.0 TB/s write.
// ---------------------------------------------------------------------------
__global__ __launch_bounds__(256) void gemm_kernel(const u16* __restrict__ Abf,
                                                   const u16* __restrict__ WcatT,
                                                   const float* __restrict__ bcat,
                                                   u16* __restrict__ G,
                                                   float* __restrict__ Acc,
                                                   float* __restrict__ Bcc) {
  __shared__ __align__(16) u16 sm[16384];   // As(16KB) + Bs(16KB); reused as C-tile
  u16* As = sm;
  u16* Bs = sm + 8192;
  const int tid = threadIdx.x;
  const int lane = tid & 63, wave = tid >> 6;
  const int wm = wave >> 1, wn = wave & 1;
  const int q = lane >> 4, r = lane & 15;

  const int xcd = blockIdx.x & 7;
  const int li  = blockIdx.x >> 3;
  const int mt  = xcd * 64 + li / 12;
  const int nt  = li % 12;
  const int m0 = mt * 128, n0 = nt * 128;

  const u16* gA[4]; const u16* gB[4]; u16* lA[4]; u16* lB[4];
#pragma unroll
  for (int j = 0; j < 4; j++) {
    const int bi = wave * 256 + j * 64 + lane;   // LDS 16B-slot idx
    const int row = bi >> 3;
    const int kq = (bi & 7) ^ (row & 7);         // logical k-block for this slot
    gA[j] = Abf   + (size_t)(m0 + row) * KDIM + kq * 8;
    gB[j] = WcatT + (size_t)(n0 + row) * KDIM + kq * 8;
    lA[j] = As + bi * 8;
    lB[j] = Bs + bi * 8;
  }

  floatx4 acc[4][4];
  floatx4 z4 = {0.f, 0.f, 0.f, 0.f};
#pragma unroll
  for (int i = 0; i < 4; i++)
#pragma unroll
    for (int j = 0; j < 4; j++) acc[i][j] = z4;

  for (int k0 = 0; k0 < KDIM; k0 += 64) {
#pragma unroll
    for (int j = 0; j < 4; j++) { gll16(gA[j] + k0, lA[j]); gll16(gB[j] + k0, lB[j]); }
    __syncthreads();
#pragma unroll
    for (int kk = 0; kk < 2; kk++) {
      bf16x8 af[4], bv[4];
#pragma unroll
      for (int i = 0; i < 4; i++) {
        const int row = wm * 64 + i * 16 + r;
        af[i] = *(const bf16x8*)(As + (row * 8 + ((kk * 4 + q) ^ (row & 7))) * 8);
      }
#pragma unroll
      for (int j = 0; j < 4; j++) {
        const int row = wn * 64 + j * 16 + r;
        bv[j] = *(const bf16x8*)(Bs + (row * 8 + ((kk * 4 + q) ^ (row & 7))) * 8);
      }
#pragma unroll
      for (int i = 0; i < 4; i++)
#pragma unroll
        for (int j = 0; j < 4; j++)
          acc[i][j] = __builtin_amdgcn_mfma_f32_16x16x32_bf16(af[i], bv[j], acc[i][j], 0, 0, 0);
    }
    __syncthreads();
  }

  // Epilogue. C/D layout: col = lane&15, row = (lane>>4)*4 + reg  [m89/m91].
  const int pcol = wn * 64 + (r << 2);
  const float4 bv4 = *(const float4*)(bcat + n0 + pcol);
  const int hz = (n0 % 768) < 512;   // block-uniform

  if (hz) {
    // Stage bias-added bf16 C-tile to LDS (no global stores yet).
#pragma unroll
    for (int i = 0; i < 4; i++) {
#pragma unroll
      for (int reg = 0; reg < 4; reg++) {
        const int lrow = wm * 64 + i * 16 + q * 4 + reg;
        union { u16 u[4]; u32x2 v; } t;
        t.u[0] = f2bf(acc[i][0][reg] + bv4.x);
        t.u[1] = f2bf(acc[i][1][reg] + bv4.y);
        t.u[2] = f2bf(acc[i][2][reg] + bv4.z);
        t.u[3] = f2bf(acc[i][3][reg] + bv4.w);
        *(u32x2*)(sm + lrow * 128 + pcol) = t.v;
      }
    }

    __syncthreads();   // vmcnt already 0 -> free drain; orders the LDS tile

    // Coalesced G write: 8 passes x 16B/thread, 256B segments per row.
#pragma unroll
    for (int p = 0; p < 8; p++) {
      const int idx = p * 2048 + tid * 8;        // u16 index within tile
      const int row = idx >> 7, col = idx & 127;
      const u32x4 v = *(const u32x4*)(sm + idx);
      *(u32x4*)(G + (size_t)(m0 + row) * NDIM + n0 + col) = v;
    }

    // 4 chunks (one per wave) x 64 d (one per lane); 32-step affine summary.
    const int cc = wave;                 // chunk within tile 0..3
    const int dd = lane;                 // d within tile 0..63
    const int dirn = n0 / 768;
    const int dbase = (n0 % 768) >> 1;   // 0,64,128,192
    const int bb = m0 >> 13;             // batch
    const int c0 = (m0 & 8191) >> 5;     // first chunk of tile
    float h = 0.f, P = 1.f;
#pragma unroll 8
    for (int i = 0; i < TCH; ++i) {
      const int tl = dirn ? (TCH - 1 - i) : i;
      const unsigned int hzv = *(const unsigned int*)(sm + (cc * 32 + tl) * 128 + dd * 2);
      const float z = sigmoidf_fast(bf2f((u16)(hzv >> 16)));
      const float a = 1.f - z;
      h = fmaf(a, h, z * bf2f((u16)(hzv & 0xffffu)));
      P *= a;
    }
    const size_t u = (size_t)dirn * 2048 + (size_t)bb * 256 + (size_t)(c0 + cc);
    Acc[u * 256 + dbase + dd] = P;
    Bcc[u * 256 + dbase + dd] = h;
  } else {
    // s-gate block: direct 8B stores from registers, no extra barrier.
#pragma unroll
    for (int i = 0; i < 4; i++) {
#pragma unroll
      for (int reg = 0; reg < 4; reg++) {
        const int lrow = wm * 64 + i * 16 + q * 4 + reg;
        union { u16 u[4]; u32x2 v; } t;
        t.u[0] = f2bf(acc[i][0][reg] + bv4.x);
        t.u[1] = f2bf(acc[i][1][reg] + bv4.y);
        t.u[2] = f2bf(acc[i][2][reg] + bv4.z);
        t.u[3] = f2bf(acc[i][3][reg] + bv4.w);
        *(u32x2*)(G + (size_t)(m0 + lrow) * NDIM + n0 + pcol) = t.v;
      }
    }
  }
}

// ---------------------------------------------------------------------------
// Scan phase B1: two-level scan, level 1. Per (dir,b,super), overwrite
// Acc/Bcc in place with within-super prefix affines; emit super summary.
// ---------------------------------------------------------------------------
__global__ __launch_bounds__(256) void scan_phaseB1(float* __restrict__ Acc,
                                                    float* __restrict__ Bcc,
                                                    float* __restrict__ Asum,
                                                    float* __restrict__ Bsum) {
  const int d = threadIdx.x;
  const int s   = blockIdx.x & 15;
  const int b   = (blockIdx.x >> 4) & 7;
  const int dir = blockIdx.x >> 7;
  const size_t ubase = ((size_t)dir * BDIM + b) * NCH;
  float a[16], bb[16];
#pragma unroll
  for (int i = 0; i < 16; ++i) {
    const int c = dir ? (NCH - 1 - (s * 16 + i)) : (s * 16 + i);
    const size_t idx = (ubase + c) * DDIM + d;
    a[i] = Acc[idx]; bb[i] = Bcc[idx];
  }
  float A = 1.f, Bv = 0.f;
#pragma unroll
  for (int i = 0; i < 16; ++i) {
    const int c = dir ? (NCH - 1 - (s * 16 + i)) : (s * 16 + i);
    const size_t idx = (ubase + c) * DDIM + d;
    Acc[idx] = A; Bcc[idx] = Bv;
    Bv = fmaf(a[i], Bv, bb[i]);
    A  = a[i] * A;
  }
  const size_t sidx = (((size_t)dir * BDIM + b) * NSUP + s) * DDIM + d;
  Asum[sidx] = A; Bsum[sidx] = Bv;
}

// ---------------------------------------------------------------------------
// Scan phase C (B2 folded in): block = one (b,c) chunk, 256 thr, 2 d/lane,
// both dirs concurrent. Entry: chain <=15 L2-resident super summaries from
// h0, then the chunk prefix affine. G loads batched 16-deep. Staggered
// 2-phase LDS exchange.
// ---------------------------------------------------------------------------
__global__ __launch_bounds__(256) void scan_phaseC(const u16* __restrict__ G,
                                                   const float* __restrict__ Acc,
                                                   const float* __restrict__ Bcc,
                                                   const float* __restrict__ Asum,
                                                   const float* __restrict__ Bsum,
                                                   const float* __restrict__ h01,
                                                   const float* __restrict__ h0_1,
                                                   float* __restrict__ out) {
  __shared__ float obuf[TCH * 256];   // 32 KB
  const int c = blockIdx.x & 255, b = blockIdx.x >> 8;
  const int dir = threadIdx.x >> 7;                       // waves 0-1 fwd, 2-3 bwd
  const int ld  = threadIdx.x & 127;                      // 0..127 within dir
  const int d0 = ld * 2;

  // --- entry state: h0 -> chain supers < sp -> chunk prefix affine ---
  const int sp = dir ? ((NCH - 1 - c) >> 4) : (c >> 4);
  const float2 hh = dir ? *(const float2*)(h0_1 + d0) : *(const float2*)(h01 + d0);
  float ha = hh.x, hb = hh.y;
  const size_t sbase = ((size_t)dir * BDIM + b) * NSUP;
  for (int s = 0; s < sp; ++s) {
    const float2 As2 = *(const float2*)(Asum + (sbase + s) * DDIM + d0);
    const float2 Bs2 = *(const float2*)(Bsum + (sbase + s) * DDIM + d0);
    ha = fmaf(As2.x, ha, Bs2.x);
    hb = fmaf(As2.y, hb, Bs2.y);
  }
  const int u = dir * 2048 + b * 256 + c;
  const float2 ap = *(const float2*)(Acc + (size_t)u * 256 + d0);
  const float2 bp = *(const float2*)(Bcc + (size_t)u * 256 + d0);
  float h0 = fmaf(ap.x, ha, bp.x);
  float h1 = fmaf(ap.y, hb, bp.y);

  const u16* ghz = G + (size_t)b * LDIM * NDIM + dir * 768 + d0 * 2;
  const u16* gs  = G + (size_t)b * LDIM * NDIM + dir * 768 + 512 + d0;

  // Phase 1: fwd tl=0..15, bwd tl=31..16 (disjoint obuf rows).
  {
    uint2 hzr[16]; unsigned int sr[16];
#pragma unroll
    for (int i = 0; i < 16; ++i) {
      const int tl = dir ? (TCH - 1 - i) : i;
      const int t = c * TCH + tl;
      hzr[i] = *(const uint2*)(ghz + (size_t)t * NDIM);
      sr[i]  = *(const unsigned int*)(gs + (size_t)t * NDIM);
    }
#pragma unroll
    for (int i = 0; i < 16; ++i) {
      const int tl = dir ? (TCH - 1 - i) : i;
      const float z0 = sigmoidf_fast(bf2f((u16)(hzr[i].x >> 16)));
      const float z1 = sigmoidf_fast(bf2f((u16)(hzr[i].y >> 16)));
      h0 = fmaf(1.f - z0, h0, z0 * bf2f((u16)(hzr[i].x & 0xffffu)));
      h1 = fmaf(1.f - z1, h1, z1 * bf2f((u16)(hzr[i].y & 0xffffu)));
      float2 o;
      o.x = h0 * sigmoidf_fast(bf2f((u16)(sr[i] & 0xffffu)));
      o.y = h1 * sigmoidf_fast(bf2f((u16)(sr[i] >> 16)));
      *(float2*)(obuf + tl * 256 + d0) = o;
    }
  }

  __syncthreads();

  // Phase 2: fwd tl=16..31, bwd tl=15..0; merge with other dir, store out.
  {
    uint2 hzr[16]; unsigned int sr[16];
#pragma unroll
    for (int i = 0; i < 16; ++i) {
      const int tl = dir ? (TCH - 1 - (16 + i)) : (16 + i);
      const int t = c * TCH + tl;
      hzr[i] = *(const uint2*)(ghz + (size_t)t * NDIM);
      sr[i]  = *(const unsigned int*)(gs + (size_t)t * NDIM);
    }
#pragma unroll
    for (int i = 0; i < 16; ++i) {
      const int tl = dir ? (TCH - 1 - (16 + i)) : (16 + i);
      const int t = c * TCH + tl;
      const float z0 = sigmoidf_fast(bf2f((u16)(hzr[i].x >> 16)));
      const float z1 = sigmoidf_fast(bf2f((u16)(hzr[i].y >> 16)));
      h0 = fmaf(1.f - z0, h0, z0 * bf2f((u16)(hzr[i].x & 0xffffu)));
      h1 = fmaf(1.f - z1, h1, z1 * bf2f((u16)(hzr[i].y & 0xffffu)));
      const float o0 = h0 * sigmoidf_fast(bf2f((u16)(sr[i] & 0xffffu)));
      const float o1 = h1 * sigmoidf_fast(bf2f((u16)(sr[i] >> 16)));
      const float2 other = *(const float2*)(obuf + tl * 256 + d0);
      float2 res;
      res.x = o0 + other.x;
      res.y = o1 + other.y;
      *(float2*)(out + ((size_t)b * LDIM + t) * DDIM + d0) = res;
    }
  }
}

extern "C" void kernel_launch(void* const* d_in, const int* in_sizes, int n_in,
                              void* d_out, int out_size, void* d_ws, size_t ws_size,
                              hipStream_t stream) {
  const float* xs   = (const float*)d_in[0];
  const float* Wh1  = (const float*)d_in[1];
  const float* bh1  = (const float*)d_in[2];
  const float* Wz1  = (const float*)d_in[3];
  const float* bz1  = (const float*)d_in[4];
  const float* Ws1  = (const float*)d_in[5];
  const float* bs1  = (const float*)d_in[6];
  const float* h01  = (const float*)d_in[7];
  const float* Wh_1 = (const float*)d_in[8];
  const float* bh_1 = (const float*)d_in[9];
  const float* Wz_1 = (const float*)d_in[10];
  const float* bz_1 = (const float*)d_in[11];
  const float* Ws_1 = (const float*)d_in[12];
  const float* bs_1 = (const float*)d_in[13];
  const float* h0_1 = (const float*)d_in[14];
  float* out = (float*)d_out;

  char* ws = (char*)d_ws;
  u16* WcatT = (u16*)ws;   ws += (size_t)NDIM * KDIM * 2;   // 0.75 MB
  float* bcat = (float*)ws; ws += (size_t)NDIM * 4;         // 6 KB
  u16* Abf = (u16*)ws;     ws += (size_t)MTOT * KDIM * 2;   // 32 MB
  u16* G = (u16*)ws;       ws += (size_t)MTOT * NDIM * 2;   // 192 MB

  const size_t sumElems = (size_t)2 * BDIM * NCH * DDIM;    // 1M floats = 4 MB
  const size_t supElems = (size_t)2 * BDIM * NSUP * DDIM;   // 64K floats = 256 KB
  float* Acc  = (float*)ws; ws += sumElems * 4;
  float* Bcc  = (float*)ws; ws += sumElems * 4;
  float* Asum = (float*)ws; ws += supElems * 4;
  float* Bsum = (float*)ws; ws += supElems * 4;
  if ((size_t)(ws - (char*)d_ws) > ws_size) return;

  prep_conv<<<dim3(NDIM + 2048), dim3(256), 0, stream>>>(
      Wh1, Wz1, Ws1, Wh_1, Wz_1, Ws_1, bh1, bz1, bs1, bh_1, bz_1, bs_1,
      WcatT, bcat, xs, Abf);
  gemm_kernel<<<dim3(6144), dim3(256), 0, stream>>>(Abf, WcatT, bcat, G, Acc, Bcc);
  scan_phaseB1<<<dim3(256), dim3(DDIM), 0, stream>>>(Acc, Bcc, Asum, Bsum);
  scan_phaseC<<<dim3(2048), dim3(256), 0, stream>>>(G, Acc, Bcc, Asum, Bsum, h01, h0_1, out);
}